// Round 1
// baseline (15459.912 us; speedup 1.0000x reference)
//
#include <hip/hip_runtime.h>
#include <math.h>

#define NTHR 256

// ---------------- per-batch workspace layout (floats) ----------------
// e levels 1..8: rows(l)=256>>l, each row 128 floats; level 0 (root) is
// uniform E_obs[2] and never stored.
constexpr int CMAX = 32;                      // max rows per MLP chunk
constexpr int E_TOTAL   = 32640;              // (128+64+...+1)*128
constexpr int Z_OFF     = E_TOTAL;            // z scratch: CMAX x 384
constexpr int H_OFF     = Z_OFF + CMAX * 384; // h scratch: CMAX x 256
constexpr int WS_STRIDE = H_OFF + CMAX * 256; // 53120 floats per batch

__device__ __forceinline__ int eoff(int l) { return (256 - (512 >> l)) * 128; } // l in 1..8
__device__ __forceinline__ int xoff(int l) { return 512 - (512 >> l); }         // l in 0..7

// ---------------- one MLP chunk: out = relu(z@W1+b1)@W2+b2 ----------------
// z: C x KIN (global scratch), h: C x 256, eout: C x 128.
// Layer1: thread t owns hidden column k=t; weights coalesced, z broadcast.
// Layer2: thread t owns (d = t&127, row parity rh = t>>7).
template <int KIN, int C>
__device__ void mlp_chunk(const float* __restrict__ z,
                          const float* __restrict__ W1, const float* __restrict__ B1,
                          const float* __restrict__ W2, const float* __restrict__ B2,
                          float* __restrict__ h, float* __restrict__ eout)
{
  const int t = threadIdx.x;
  {
    float acc[C];
#pragma unroll
    for (int r = 0; r < C; ++r) acc[r] = 0.0f;
    const float* Wp = W1 + t;
    for (int kk = 0; kk < KIN; kk += 4) {
      const float w0 = Wp[(kk + 0) * 256];
      const float w1 = Wp[(kk + 1) * 256];
      const float w2 = Wp[(kk + 2) * 256];
      const float w3 = Wp[(kk + 3) * 256];
#pragma unroll
      for (int r = 0; r < C; ++r) {
        const float4 z4 = *reinterpret_cast<const float4*>(z + r * KIN + kk);
        acc[r] = fmaf(z4.x, w0, acc[r]);
        acc[r] = fmaf(z4.y, w1, acc[r]);
        acc[r] = fmaf(z4.z, w2, acc[r]);
        acc[r] = fmaf(z4.w, w3, acc[r]);
      }
    }
    const float bias = B1[t];
#pragma unroll
    for (int r = 0; r < C; ++r) {
      const float v = acc[r] + bias;
      h[r * 256 + t] = v > 0.0f ? v : 0.0f;
    }
  }
  __syncthreads();
  {
    const int d  = t & 127;
    const int rh = t >> 7;
    constexpr int CR = (C + 1) / 2;
    float acc[CR];
#pragma unroll
    for (int j = 0; j < CR; ++j) acc[j] = 0.0f;
    const float* Wp = W2 + d;
    for (int k = 0; k < 256; k += 4) {
      const float w0 = Wp[(k + 0) * 128];
      const float w1 = Wp[(k + 1) * 128];
      const float w2 = Wp[(k + 2) * 128];
      const float w3 = Wp[(k + 3) * 128];
#pragma unroll
      for (int j = 0; j < CR; ++j) {
        const int r = rh + 2 * j;
        if (r < C) {
          const float4 h4 = *reinterpret_cast<const float4*>(h + r * 256 + k);
          acc[j] = fmaf(h4.x, w0, acc[j]);
          acc[j] = fmaf(h4.y, w1, acc[j]);
          acc[j] = fmaf(h4.z, w2, acc[j]);
          acc[j] = fmaf(h4.w, w3, acc[j]);
        }
      }
    }
    const float bias = B2[d];
#pragma unroll
    for (int j = 0; j < CR; ++j) {
      const int r = rh + 2 * j;
      if (r < C) eout[r * 128 + d] = acc[j] + bias;
    }
  }
}

// ---------------- one stage (check: KIN=256, bit: KIN=384) ----------------
// ein == nullptr means the virtual root embedding (uniform E_obs[2]).
// u1h: LDS pointer to left-child hard bits (bit stages only).
template <int KIN>
__device__ void run_stage(const float* ein, int rows, const int* u1h,
                          const float* __restrict__ W1, const float* __restrict__ B1,
                          const float* __restrict__ W2, const float* __restrict__ B2,
                          const float* __restrict__ eobs2, const float* __restrict__ elab,
                          float* __restrict__ z_ws, float* __restrict__ h_ws,
                          float* __restrict__ eout)
{
  int done = 0;
  while (done < rows) {
    int c = rows - done;
    if (c > CMAX) c = CMAX;
    // build z chunk: z[r] = concat(e[2r], e[2r+1] [, E_lab[u1h[r]]])
    for (int r = 0; r < c; ++r) {
      const int gr = done + r;
      for (int col = threadIdx.x; col < KIN; col += NTHR) {
        float v;
        if (col < 256) {
          v = ein ? ein[(2 * gr + (col >> 7)) * 128 + (col & 127)] : eobs2[col & 127];
        } else {
          v = elab[u1h[gr] * 128 + (col - 256)];
        }
        z_ws[r * KIN + col] = v;
      }
    }
    __syncthreads();
    float* eo = eout + done * 128;
    switch (c) {
      case 32: mlp_chunk<KIN, 32>(z_ws, W1, B1, W2, B2, h_ws, eo); break;
      case 16: mlp_chunk<KIN, 16>(z_ws, W1, B1, W2, B2, h_ws, eo); break;
      case 8:  mlp_chunk<KIN, 8 >(z_ws, W1, B1, W2, B2, h_ws, eo); break;
      case 4:  mlp_chunk<KIN, 4 >(z_ws, W1, B1, W2, B2, h_ws, eo); break;
      case 2:  mlp_chunk<KIN, 2 >(z_ws, W1, B1, W2, B2, h_ws, eo); break;
      default: mlp_chunk<KIN, 1 >(z_ws, W1, B1, W2, B2, h_ws, eo); break;
    }
    __syncthreads();
    done += c;
  }
}

__global__ void sc_setup(const int* __restrict__ info_set, int* __restrict__ pos2k)
{
  const int t = threadIdx.x;
  pos2k[t] = -1;
  __syncthreads();
  if (t < 128) pos2k[info_set[t]] = t;
}

__global__ __launch_bounds__(NTHR, 1)
void sc_main(const int* __restrict__ info_bits, const float* __restrict__ rin,
             const float* __restrict__ E_obs, const float* __restrict__ E_lab,
             const float* __restrict__ Wc1, const float* __restrict__ bc1,
             const float* __restrict__ Wc2, const float* __restrict__ bc2,
             const float* __restrict__ Wb1, const float* __restrict__ bb1,
             const float* __restrict__ Wb2, const float* __restrict__ bb2,
             const float* __restrict__ Wl, const float* __restrict__ bl,
             const int* __restrict__ pos2k,
             float* __restrict__ wsall, float* __restrict__ out)
{
  const int b = blockIdx.x;   // one block per batch element
  const int t = threadIdx.x;
  float* bws = wsall + (size_t)b * WS_STRIDE;
  float* zt  = bws + Z_OFF;
  float* ht  = bws + H_OFF;
  const float* eobs2 = E_obs + 2 * 128;

  // hard-bit tree: xh[level] holds the two children's bits of the active node
  __shared__ int xh[512];

  float* xO = out;
  float* fO = out + 32768;
  float* uO = out + 65536;
  float* pO = out + 98304;
  float* rO = out + 131072;

  auto ebuf = [&](int l) -> float* { return bws + eoff(l); };

  auto do_check = [&](int l) {
    const float* ein = (l == 0) ? nullptr : ebuf(l);
    run_stage<256>(ein, 128 >> l, nullptr, Wc1, bc1, Wc2, bc2, eobs2, nullptr,
                   zt, ht, ebuf(l + 1));
  };
  auto do_bit = [&](int l) {
    const float* ein = (l == 0) ? nullptr : ebuf(l);
    run_stage<384>(ein, 128 >> l, xh + xoff(l), Wb1, bb1, Wb2, bb2, eobs2, E_lab,
                   zt, ht, ebuf(l + 1));
  };
  auto do_leaf = [&](int i) {
    const float* e = ebuf(8);  // 1 row, 128 floats
    if (t < 64) {
      float partial = e[t] * Wl[t] + e[t + 64] * Wl[t + 64];
#pragma unroll
      for (int m = 32; m >= 1; m >>= 1) partial += __shfl_xor(partial, m);
      if (t == 0) {
        const float tv = partial + bl[0];
        const float p  = 1.0f / (1.0f + expf(-tv));
        const float rv = rin[b * 256 + i];
        const int  hd     = (rv > p) ? 1 : 0;
        const bool frozen = fabsf(p - 0.5f) > 0.25f;
        const int  k  = pos2k[i];
        const int  fc = (k >= 0) ? info_bits[b * 128 + k] : 2;
        const int  x  = (fc == 2 || frozen) ? hd : fc;
        xh[xoff(7) + (i & 1)] = x;
        pO[b * 256 + i] = p;
        uO[b * 256 + i] = (float)x;
        fO[b * 256 + i] = (k >= 0) ? 2.0f : 1.0f;
        rO[b * 256 + i] = rv;
      }
    }
    __syncthreads();
  };
  auto do_combine = [&](int l, int side) {
    const int n = 256 >> l, half = n >> 1;
    if (t < half) {
      const int u1 = xh[xoff(l) + t];
      const int u2 = xh[xoff(l) + half + t];
      if (l > 0) {
        const int base = xoff(l - 1) + side * n;
        xh[base + 2 * t]     = u1 ^ u2;
        xh[base + 2 * t + 1] = u2;
      } else {
        xO[b * 256 + 2 * t]     = (float)(u1 ^ u2);
        xO[b * 256 + 2 * t + 1] = (float)u2;
      }
    }
    __syncthreads();
  };

  // initial descent to leaf 0
  for (int l = 0; l < 8; ++l) do_check(l);
  do_leaf(0);

  for (int i = 1; i < 256; ++i) {
    const int s = __builtin_ctz(i);
    // fold completed subtrees upward; last fold lands as u1h (side 0)
    for (int j = 1; j <= s; ++j) do_combine(8 - j, (j < s) ? 1 : 0);
    const int lb = 7 - s;
    do_bit(lb);
    for (int l = lb + 1; l < 8; ++l) do_check(l);
    do_leaf(i);
  }
  // final folds; level-0 combine writes the codeword x
  for (int j = 1; j <= 8; ++j) do_combine(8 - j, 1);
}

extern "C" void kernel_launch(void* const* d_in, const int* in_sizes, int n_in,
                              void* d_out, int out_size, void* d_ws, size_t ws_size,
                              hipStream_t stream)
{
  const int*   info_bits = (const int*)  d_in[0];
  const float* rin       = (const float*)d_in[1];
  const int*   info_set  = (const int*)  d_in[2];
  const float* E_obs     = (const float*)d_in[3];
  const float* E_lab     = (const float*)d_in[4];
  const float* Wc1 = (const float*)d_in[5];
  const float* bc1 = (const float*)d_in[6];
  const float* Wc2 = (const float*)d_in[7];
  const float* bc2 = (const float*)d_in[8];
  const float* Wb1 = (const float*)d_in[9];
  const float* bb1 = (const float*)d_in[10];
  const float* Wb2 = (const float*)d_in[11];
  const float* bb2 = (const float*)d_in[12];
  const float* Wl  = (const float*)d_in[13];
  const float* bl  = (const float*)d_in[14];

  int*   pos2k = (int*)d_ws;
  float* wsall = (float*)d_ws + 256;

  hipLaunchKernelGGL(sc_setup, dim3(1), dim3(256), 0, stream, info_set, pos2k);
  hipLaunchKernelGGL(sc_main, dim3(128), dim3(NTHR), 0, stream,
                     info_bits, rin, E_obs, E_lab,
                     Wc1, bc1, Wc2, bc2, Wb1, bb1, Wb2, bb2, Wl, bl,
                     pos2k, wsall, (float*)d_out);
}

// Round 2
// 11098.083 us; speedup vs baseline: 1.3930x; 1.3930x over previous
//
#include <hip/hip_runtime.h>
#include <math.h>

#define NTHR 1024

// ---------------- per-batch workspace layout (floats) ----------------
// e levels 1..8: rows(l)=256>>l, each row 128 floats; level 0 (root) is
// uniform E_obs[2] and never stored.
constexpr int CMAX = 16;                      // max rows per MLP chunk
constexpr int E_TOTAL   = 32640;              // (128+64+...+1)*128
constexpr int WS_STRIDE = E_TOTAL;            // floats per batch

__device__ __forceinline__ int eoff(int l) { return (256 - (512 >> l)) * 128; } // l in 1..8
__device__ __forceinline__ int xoff(int l) { return 512 - (512 >> l); }         // l in 0..7

// ---------------- one MLP chunk: out = relu(z@W1+b1)@W2+b2 ----------------
// z: C x KIN (LDS), h: C x 256 (LDS), red: 2048-float LDS scratch,
// eout: C x 128 (global e-buffer).
// Layer1 (hidden=256): 1024 thr = 256 hidden x 4 slices.
//   C>=4 : slice s owns rows r = s+4j (full K per thread).
//   C<4  : slice s owns K-quarter [s*KIN/4 ..), partials reduced via LDS.
// Layer2 (out=128, K=256): 1024 thr = 128 outs x 8 slices.
//   C>=8 : slice q owns rows r = q+8j (full K).
//   C<8  : q = ks*C + r, K-slice of 256*C/8, partials reduced via LDS.
template <int KIN, int C>
__device__ void mlp_chunk(const float* __restrict__ z,
                          const float* __restrict__ W1, const float* __restrict__ B1,
                          const float* __restrict__ W2, const float* __restrict__ B2,
                          float* __restrict__ h, float* __restrict__ red,
                          float* __restrict__ eout)
{
  const int t = threadIdx.x;
  // ---------------- layer 1 ----------------
  {
    const int hcol = t & 255;
    const int s    = t >> 8;        // 0..3
    const float* Wp = W1 + hcol;
    if (C >= 4) {
      constexpr int RP = (C + 3) / 4;
      float acc[RP];
#pragma unroll
      for (int j = 0; j < RP; ++j) acc[j] = 0.0f;
      for (int kk = 0; kk < KIN; kk += 4) {
        const float w0 = Wp[(kk + 0) * 256];
        const float w1 = Wp[(kk + 1) * 256];
        const float w2 = Wp[(kk + 2) * 256];
        const float w3 = Wp[(kk + 3) * 256];
#pragma unroll
        for (int j = 0; j < RP; ++j) {
          const int r = s + 4 * j;
          if (r < C) {
            const float4 z4 = *reinterpret_cast<const float4*>(z + r * KIN + kk);
            acc[j] = fmaf(z4.x, w0, acc[j]);
            acc[j] = fmaf(z4.y, w1, acc[j]);
            acc[j] = fmaf(z4.z, w2, acc[j]);
            acc[j] = fmaf(z4.w, w3, acc[j]);
          }
        }
      }
      const float bias = B1[hcol];
#pragma unroll
      for (int j = 0; j < RP; ++j) {
        const int r = s + 4 * j;
        if (r < C) {
          const float v = acc[j] + bias;
          h[r * 256 + hcol] = v > 0.0f ? v : 0.0f;
        }
      }
      __syncthreads();
    } else {
      constexpr int KS = KIN / 4;
      const int k0 = s * KS;
      float acc[C];
#pragma unroll
      for (int r = 0; r < C; ++r) acc[r] = 0.0f;
      for (int kk = k0; kk < k0 + KS; kk += 4) {
        const float w0 = Wp[(kk + 0) * 256];
        const float w1 = Wp[(kk + 1) * 256];
        const float w2 = Wp[(kk + 2) * 256];
        const float w3 = Wp[(kk + 3) * 256];
#pragma unroll
        for (int r = 0; r < C; ++r) {
          const float4 z4 = *reinterpret_cast<const float4*>(z + r * KIN + kk);
          acc[r] = fmaf(z4.x, w0, acc[r]);
          acc[r] = fmaf(z4.y, w1, acc[r]);
          acc[r] = fmaf(z4.z, w2, acc[r]);
          acc[r] = fmaf(z4.w, w3, acc[r]);
        }
      }
#pragma unroll
      for (int r = 0; r < C; ++r) red[(s * C + r) * 256 + hcol] = acc[r];
      __syncthreads();
      if (t < 256 * C) {
        const int h2 = t & 255, r2 = t >> 8;
        float sum = red[(0 * C + r2) * 256 + h2] + red[(1 * C + r2) * 256 + h2]
                  + red[(2 * C + r2) * 256 + h2] + red[(3 * C + r2) * 256 + h2];
        sum += B1[h2];
        h[r2 * 256 + h2] = sum > 0.0f ? sum : 0.0f;
      }
      __syncthreads();
    }
  }
  // ---------------- layer 2 ----------------
  {
    const int d = t & 127;
    const int q = t >> 7;          // 0..7
    const float* Wp = W2 + d;
    if (C >= 8) {
      constexpr int RP2 = (C + 7) / 8;
      float acc[RP2];
#pragma unroll
      for (int j = 0; j < RP2; ++j) acc[j] = 0.0f;
      for (int k = 0; k < 256; k += 4) {
        const float w0 = Wp[(k + 0) * 128];
        const float w1 = Wp[(k + 1) * 128];
        const float w2 = Wp[(k + 2) * 128];
        const float w3 = Wp[(k + 3) * 128];
#pragma unroll
        for (int j = 0; j < RP2; ++j) {
          const int r = q + 8 * j;
          if (r < C) {
            const float4 h4 = *reinterpret_cast<const float4*>(h + r * 256 + k);
            acc[j] = fmaf(h4.x, w0, acc[j]);
            acc[j] = fmaf(h4.y, w1, acc[j]);
            acc[j] = fmaf(h4.z, w2, acc[j]);
            acc[j] = fmaf(h4.w, w3, acc[j]);
          }
        }
      }
      const float bias = B2[d];
#pragma unroll
      for (int j = 0; j < RP2; ++j) {
        const int r = q + 8 * j;
        if (r < C) eout[r * 128 + d] = acc[j] + bias;
      }
      __syncthreads();
    } else {
      constexpr int KS2 = 256 * C / 8;          // K per slice
      const int r  = q & (C - 1);
      const int ks = q / C;
      const int k0 = ks * KS2;
      float acc = 0.0f;
      for (int k = k0; k < k0 + KS2; k += 4) {
        const float w0 = Wp[(k + 0) * 128];
        const float w1 = Wp[(k + 1) * 128];
        const float w2 = Wp[(k + 2) * 128];
        const float w3 = Wp[(k + 3) * 128];
        const float4 h4 = *reinterpret_cast<const float4*>(h + r * 256 + k);
        acc = fmaf(h4.x, w0, acc);
        acc = fmaf(h4.y, w1, acc);
        acc = fmaf(h4.z, w2, acc);
        acc = fmaf(h4.w, w3, acc);
      }
      red[q * 128 + d] = acc;   // q*128+d == (ks*C+r)*128+d
      __syncthreads();
      if (t < 128 * C) {
        const int d2 = t & 127, r2 = t >> 7;
        float sum = B2[d2];
#pragma unroll
        for (int ks2 = 0; ks2 < 8 / C; ++ks2) sum += red[(ks2 * C + r2) * 128 + d2];
        eout[r2 * 128 + d2] = sum;
      }
      __syncthreads();
    }
  }
}

// ---------------- one stage (check: KIN=256, bit: KIN=384) ----------------
template <int KIN>
__device__ void run_stage(const float* ein, int rows, const int* u1h,
                          const float* __restrict__ W1, const float* __restrict__ B1,
                          const float* __restrict__ W2, const float* __restrict__ B2,
                          const float* __restrict__ eobs2, const float* __restrict__ elab,
                          float* __restrict__ z_lds, float* __restrict__ h_lds,
                          float* __restrict__ red_lds,
                          float* __restrict__ eout)
{
  const int t = threadIdx.x;
  int done = 0;
  while (done < rows) {
    int c = rows - done;
    if (c > CMAX) c = CMAX;
    // build z chunk in LDS: z[r] = concat(e[2r], e[2r+1] [, E_lab[u1h[r]]])
    const int total = c * KIN;
    for (int idx = t; idx < total; idx += NTHR) {
      int r, col;
      if (KIN == 256) { r = idx >> 8; col = idx & 255; }
      else            { r = idx / 384; col = idx - r * 384; }
      const int gr = done + r;
      float v;
      if (col < 256) {
        v = ein ? ein[(2 * gr + (col >> 7)) * 128 + (col & 127)] : eobs2[col & 127];
      } else {
        v = elab[u1h[gr] * 128 + (col - 256)];
      }
      z_lds[r * KIN + col] = v;
    }
    __syncthreads();
    float* eo = eout + done * 128;
    switch (c) {
      case 16: mlp_chunk<KIN, 16>(z_lds, W1, B1, W2, B2, h_lds, red_lds, eo); break;
      case 8:  mlp_chunk<KIN, 8 >(z_lds, W1, B1, W2, B2, h_lds, red_lds, eo); break;
      case 4:  mlp_chunk<KIN, 4 >(z_lds, W1, B1, W2, B2, h_lds, red_lds, eo); break;
      case 2:  mlp_chunk<KIN, 2 >(z_lds, W1, B1, W2, B2, h_lds, red_lds, eo); break;
      default: mlp_chunk<KIN, 1 >(z_lds, W1, B1, W2, B2, h_lds, red_lds, eo); break;
    }
    __syncthreads();
    done += c;
  }
}

__global__ void sc_setup(const int* __restrict__ info_set, int* __restrict__ pos2k)
{
  const int t = threadIdx.x;
  pos2k[t] = -1;
  __syncthreads();
  if (t < 128) pos2k[info_set[t]] = t;
}

__global__ __launch_bounds__(NTHR, 4)
void sc_main(const int* __restrict__ info_bits, const float* __restrict__ rin,
             const float* __restrict__ E_obs, const float* __restrict__ E_lab,
             const float* __restrict__ Wc1, const float* __restrict__ bc1,
             const float* __restrict__ Wc2, const float* __restrict__ bc2,
             const float* __restrict__ Wb1, const float* __restrict__ bb1,
             const float* __restrict__ Wb2, const float* __restrict__ bb2,
             const float* __restrict__ Wl, const float* __restrict__ bl,
             const int* __restrict__ pos2k,
             float* __restrict__ wsall, float* __restrict__ out)
{
  const int b = blockIdx.x;   // one block per batch element
  const int t = threadIdx.x;
  float* bws = wsall + (size_t)b * WS_STRIDE;
  const float* eobs2 = E_obs + 2 * 128;

  __shared__ float z_lds[CMAX * 384];   // 24 KB
  __shared__ float h_lds[CMAX * 256];   // 16 KB
  __shared__ float red_lds[2048];       //  8 KB
  __shared__ int   xh[512];             //  2 KB

  float* xO = out;
  float* fO = out + 32768;
  float* uO = out + 65536;
  float* pO = out + 98304;
  float* rO = out + 131072;

  auto ebuf = [&](int l) -> float* { return bws + eoff(l); };

  auto do_check = [&](int l) {
    const float* ein = (l == 0) ? nullptr : ebuf(l);
    run_stage<256>(ein, 128 >> l, nullptr, Wc1, bc1, Wc2, bc2, eobs2, nullptr,
                   z_lds, h_lds, red_lds, ebuf(l + 1));
  };
  auto do_bit = [&](int l) {
    const float* ein = (l == 0) ? nullptr : ebuf(l);
    run_stage<384>(ein, 128 >> l, xh + xoff(l), Wb1, bb1, Wb2, bb2, eobs2, E_lab,
                   z_lds, h_lds, red_lds, ebuf(l + 1));
  };
  auto do_leaf = [&](int i) {
    const float* e = ebuf(8);  // 1 row, 128 floats
    if (t < 64) {
      float partial = e[t] * Wl[t] + e[t + 64] * Wl[t + 64];
#pragma unroll
      for (int m = 32; m >= 1; m >>= 1) partial += __shfl_xor(partial, m);
      if (t == 0) {
        const float tv = partial + bl[0];
        const float p  = 1.0f / (1.0f + expf(-tv));
        const float rv = rin[b * 256 + i];
        const int  hd     = (rv > p) ? 1 : 0;
        const bool frozen = fabsf(p - 0.5f) > 0.25f;
        const int  k  = pos2k[i];
        const int  fc = (k >= 0) ? info_bits[b * 128 + k] : 2;
        const int  x  = (fc == 2 || frozen) ? hd : fc;
        xh[xoff(7) + (i & 1)] = x;
        pO[b * 256 + i] = p;
        uO[b * 256 + i] = (float)x;
        fO[b * 256 + i] = (k >= 0) ? 2.0f : 1.0f;
        rO[b * 256 + i] = rv;
      }
    }
    __syncthreads();
  };
  auto do_combine = [&](int l, int side) {
    const int n = 256 >> l, half = n >> 1;
    if (t < half) {
      const int u1 = xh[xoff(l) + t];
      const int u2 = xh[xoff(l) + half + t];
      if (l > 0) {
        const int base = xoff(l - 1) + side * n;
        xh[base + 2 * t]     = u1 ^ u2;
        xh[base + 2 * t + 1] = u2;
      } else {
        xO[b * 256 + 2 * t]     = (float)(u1 ^ u2);
        xO[b * 256 + 2 * t + 1] = (float)u2;
      }
    }
    __syncthreads();
  };

  // initial descent to leaf 0
  for (int l = 0; l < 8; ++l) do_check(l);
  do_leaf(0);

  for (int i = 1; i < 256; ++i) {
    const int s = __builtin_ctz(i);
    // fold completed subtrees upward; last fold lands as u1h (side 0)
    for (int j = 1; j <= s; ++j) do_combine(8 - j, (j < s) ? 1 : 0);
    const int lb = 7 - s;
    do_bit(lb);
    for (int l = lb + 1; l < 8; ++l) do_check(l);
    do_leaf(i);
  }
  // final folds; level-0 combine writes the codeword x
  for (int j = 1; j <= 8; ++j) do_combine(8 - j, 1);
}

extern "C" void kernel_launch(void* const* d_in, const int* in_sizes, int n_in,
                              void* d_out, int out_size, void* d_ws, size_t ws_size,
                              hipStream_t stream)
{
  const int*   info_bits = (const int*)  d_in[0];
  const float* rin       = (const float*)d_in[1];
  const int*   info_set  = (const int*)  d_in[2];
  const float* E_obs     = (const float*)d_in[3];
  const float* E_lab     = (const float*)d_in[4];
  const float* Wc1 = (const float*)d_in[5];
  const float* bc1 = (const float*)d_in[6];
  const float* Wc2 = (const float*)d_in[7];
  const float* bc2 = (const float*)d_in[8];
  const float* Wb1 = (const float*)d_in[9];
  const float* bb1 = (const float*)d_in[10];
  const float* Wb2 = (const float*)d_in[11];
  const float* bb2 = (const float*)d_in[12];
  const float* Wl  = (const float*)d_in[13];
  const float* bl  = (const float*)d_in[14];

  int*   pos2k = (int*)d_ws;
  float* wsall = (float*)d_ws + 256;

  hipLaunchKernelGGL(sc_setup, dim3(1), dim3(256), 0, stream, info_set, pos2k);
  hipLaunchKernelGGL(sc_main, dim3(128), dim3(NTHR), 0, stream,
                     info_bits, rin, E_obs, E_lab,
                     Wc1, bc1, Wc2, bc2, Wb1, bb1, Wb2, bb2, Wl, bl,
                     pos2k, wsall, (float*)d_out);
}